// Round 5
// baseline (649.847 us; speedup 1.0000x reference)
//
#include <hip/hip_runtime.h>
#include <cmath>

#define HH 96
#define WW 96
#define HWsz 9216
#define CCH 256
#define OO 256
#define MTOT 36864
#define NTAP 9

using short8 = __attribute__((ext_vector_type(8))) short;
using f32x4  = __attribute__((ext_vector_type(4))) float;

__device__ __forceinline__ unsigned short f2bf(float f) {
    unsigned u = __float_as_uint(f);
    u += 0x7fff + ((u >> 16) & 1);
    return (unsigned short)(u >> 16);
}

// ---------------- prep ----------------
// wq  [t][cc][kh][o=256][j=8] bf16 : element = w[o][c=cc*32+kh*8+j][t]
// wqA [t][cc][kh][o=32][j=8]  bf16 : o>=27 zero, from w_off
// sc2/sh2 [256] : BN scale / shift(+bias)
__global__ __launch_bounds__(256) void prep_kernel(
    const float* __restrict__ w, const float* __restrict__ w_off,
    const float* __restrict__ gamma, const float* __restrict__ beta,
    const float* __restrict__ rmean, const float* __restrict__ rvar,
    const float* __restrict__ bconv,
    unsigned short* __restrict__ wq, unsigned short* __restrict__ wqA,
    float* __restrict__ sc2, float* __restrict__ sh2)
{
    int gid = blockIdx.x * 256 + threadIdx.x;
    if (gid < 589824) {
        int j = gid & 7, o = (gid >> 3) & 255, kh = (gid >> 11) & 3;
        int cc = (gid >> 13) & 7, t = gid >> 16;
        int c = cc * 32 + kh * 8 + j;
        wq[gid] = f2bf(w[(o * 256 + c) * 9 + t]);
        return;
    }
    gid -= 589824;
    if (gid < 73728) {
        int j = gid & 7, o = (gid >> 3) & 31, kh = (gid >> 8) & 3;
        int cc = (gid >> 10) & 7, t = gid >> 13;
        int c = cc * 32 + kh * 8 + j;
        wqA[gid] = (o < 27) ? f2bf(w_off[(o * 256 + c) * 9 + t]) : (unsigned short)0;
        return;
    }
    gid -= 73728;
    if (gid < 256) {
        float s = gamma[gid] * rsqrtf(rvar[gid] + 1e-5f);
        sc2[gid] = s;
        sh2[gid] = beta[gid] - rmean[gid] * s + bconv[gid] * s;
    }
}

// ---------------- build deform table (pair form, SoA [tap][pixel]) ----------------
// Per (pixel,tap): i = (row_top_base, row_bot_base), w = (wt0,wt1,wb0,wb1)
// such that val = wt0*x[i.x] + wt1*x[i.x+1] + wb0*x[i.y] + wb1*x[i.y+1]
__global__ __launch_bounds__(256) void build_table(
    const float* __restrict__ off, int2* __restrict__ tbi, float4* __restrict__ tbw)
{
    int e = blockIdx.x * 256 + threadIdx.x;
    if (e >= MTOT * NTAP) return;
    int p = e / 9, t = e - p * 9;
    int b = p / HWsz, hw = p - b * HWsz;
    int h = hw / WW, x = hw % WW;
    const float* ob = off + ((size_t)b * 32) * HWsz + hw;
    float dy = ob[(2 * t) * HWsz];
    float dx = ob[(2 * t + 1) * HWsz];
    float ml = ob[(18 + t) * HWsz];
    float m = 1.f / (1.f + __expf(-ml));
    float py = (float)(h + t / 3 - 1) + dy;
    float px = (float)(x + t % 3 - 1) + dx;
    float y0f = floorf(py), x0f = floorf(px);
    float ly = py - y0f, lx = px - x0f;
    int y0 = (int)y0f, x0 = (int)x0f;
    int y1 = y0 + 1;
    // column base and weights (elements xb, xb+1)
    int xb = min(max(x0, 0), WW - 2);
    float cw0 = (xb == x0) ? (1.f - lx) : ((xb == x0 + 1) ? lx : 0.f);
    float cw1 = (xb + 1 == x0) ? (1.f - lx) : ((xb + 1 == x0 + 1) ? lx : 0.f);
    // row weights
    float rt = (y0 >= 0 && y0 <= HH - 1) ? (1.f - ly) : 0.f;
    float rb = (y1 >= 0 && y1 <= HH - 1) ? ly : 0.f;
    int yt = min(max(y0, 0), HH - 1), yb = min(max(y1, 0), HH - 1);
    int2 iv; iv.x = yt * WW + xb; iv.y = yb * WW + xb;
    float4 wv;
    wv.x = rt * cw0 * m; wv.y = rt * cw1 * m;
    wv.z = rb * cw0 * m; wv.w = rb * cw1 * m;
    tbi[(size_t)t * MTOT + p] = iv;
    tbw[(size_t)t * MTOT + p] = wv;
}

// ---------------- implicit GEMM: barrier-free, LDS-free ----------------
// Wave = 16 pixels x NOCH out-channels. Lane l gathers pixel wp0+(l&15),
// channels (cc*32 + (l>>4)*8 .. +7) -> bilinear combine -> A-fragment direct.
// B fragments JIT per-lane from wq (L1/L2-hot). No __syncthreads anywhere.
template<int NOCH, int NCOR, bool PASS2>
__global__ __launch_bounds__(256, 3) void gemm_dcn(
    const float* __restrict__ x,
    const unsigned short* __restrict__ wq,
    const int2* __restrict__ tbi, const float4* __restrict__ tbw,
    const float* __restrict__ ep0, const float* __restrict__ ep1,
    float* __restrict__ outp)
{
    constexpr int NMF = NOCH / 16;
    const int tid  = threadIdx.x;
    const int wid  = tid >> 6;
    const int lane = tid & 63;
    const int l15  = lane & 15;
    const int kh   = lane >> 4;

    const int bid  = blockIdx.x;
    const int mblk = (bid & 7) * ((int)gridDim.x >> 3) + (bid >> 3);
    const int p0   = mblk * 64;
    const int wp0  = p0 + wid * 16;       // wave's first pixel
    const int pg   = wp0 + l15;           // lane's gather pixel
    const int img  = p0 / HWsz;           // uniform per block
    const int hw0  = pg - img * HWsz;
    const int ph   = hw0 / WW;
    const int pxx  = hw0 - ph * WW;
    const float* __restrict__ xim = x + (size_t)img * CCH * HWsz;

    f32x4 acc[NMF];
    #pragma unroll
    for (int n = 0; n < NMF; ++n) acc[n] = f32x4{0.f, 0.f, 0.f, 0.f};

    for (int t = 0; t < NTAP; ++t) {
        int it_ = 0, ib_ = 0;
        float w00_ = 0.f, w01_ = 0.f, w10_ = 0.f, w11_ = 0.f;
        if constexpr (NCOR == 4) {
            int2 iv = tbi[(size_t)t * MTOT + pg];
            float4 wv = tbw[(size_t)t * MTOT + pg];
            it_ = iv.x; ib_ = iv.y;
            w00_ = wv.x; w01_ = wv.y; w10_ = wv.z; w11_ = wv.w;
        } else {
            int yy = ph + t / 3 - 1, xx = pxx + t % 3 - 1;
            bool v = (yy >= 0) && (yy < HH) && (xx >= 0) && (xx < WW);
            it_ = v ? yy * WW + xx : 0;
            w00_ = v ? 1.f : 0.f;
        }
        #pragma unroll 1
        for (int cc = 0; cc < 8; ++cc) {
            const unsigned cb = (unsigned)(cc * 32 + kh * 8) * HWsz;
            float va[8];
            if constexpr (NCOR == 4) {
                #pragma unroll
                for (int j = 0; j < 8; ++j) {
                    const float* pt = xim + cb + (unsigned)j * HWsz;
                    float t0 = pt[it_], t1 = pt[it_ + 1];
                    float b0 = pt[ib_], b1 = pt[ib_ + 1];
                    va[j] = w00_ * t0 + w01_ * t1 + w10_ * b0 + w11_ * b1;
                }
            } else {
                #pragma unroll
                for (int j = 0; j < 8; ++j)
                    va[j] = w00_ * xim[cb + (unsigned)j * HWsz + it_];
            }
            short8 af;
            #pragma unroll
            for (int j = 0; j < 8; ++j) af[j] = (short)f2bf(va[j]);
            const unsigned short* wb = wq + (size_t)(((t * 8 + cc) * 4 + kh) * NOCH) * 8;
            #pragma unroll
            for (int n = 0; n < NMF; ++n) {
                short8 bfr = *(const short8*)(wb + (n * 16 + l15) * 8);
                acc[n] = __builtin_amdgcn_mfma_f32_16x16x32_bf16(af, bfr, acc[n], 0, 0, 0);
            }
        }
    }

    // ---- epilogue: D row = kh*4+j (contiguous pixels) -> float4 stores ----
    const int opix = wp0 - img * HWsz + kh * 4;
    #pragma unroll
    for (int n = 0; n < NMF; ++n) {
        int och = n * 16 + l15;
        float4 vv;
        if constexpr (PASS2) {
            float s0 = ep0[och], s1 = ep1[och];
            vv.x = fmaxf(fmaf(acc[n][0], s0, s1), 0.f);
            vv.y = fmaxf(fmaf(acc[n][1], s0, s1), 0.f);
            vv.z = fmaxf(fmaf(acc[n][2], s0, s1), 0.f);
            vv.w = fmaxf(fmaf(acc[n][3], s0, s1), 0.f);
            *(float4*)&outp[((size_t)img * OO + och) * HWsz + opix] = vv;
        } else {
            if (och < 27) {
                float s1 = ep0[och];
                vv.x = acc[n][0] + s1;
                vv.y = acc[n][1] + s1;
                vv.z = acc[n][2] + s1;
                vv.w = acc[n][3] + s1;
                *(float4*)&outp[((size_t)img * 32 + och) * HWsz + opix] = vv;
            }
        }
    }
}

extern "C" void kernel_launch(void* const* d_in, const int* in_sizes, int n_in,
                              void* d_out, int out_size, void* d_ws, size_t ws_size,
                              hipStream_t stream) {
    const float* input_x = (const float*)d_in[0];
    const float* w_off   = (const float*)d_in[1];
    const float* b_off   = (const float*)d_in[2];
    const float* w       = (const float*)d_in[3];
    const float* b       = (const float*)d_in[4];
    const float* gamma   = (const float*)d_in[5];
    const float* beta    = (const float*)d_in[6];
    const float* rmean   = (const float*)d_in[7];
    const float* rvar    = (const float*)d_in[8];
    float* out = (float*)d_out;

    char* p = (char*)d_ws;
    auto alloc = [&](size_t bytes) {
        char* r = p;
        p += (bytes + 255) & ~(size_t)255;
        return r;
    };
    unsigned short* wq  = (unsigned short*)alloc(589824 * 2);
    unsigned short* wqA = (unsigned short*)alloc(73728 * 2);
    int2*   tdi = (int2*)alloc((size_t)331776 * 8);
    float4* tdw = (float4*)alloc((size_t)331776 * 16);
    float* offb = (float*)alloc((size_t)4 * 32 * 9216 * 4);
    float* sc2 = (float*)alloc(256 * 4);
    float* sh2 = (float*)alloc(256 * 4);

    prep_kernel<<<2593, 256, 0, stream>>>(w, w_off, gamma, beta, rmean, rvar, b,
                                          wq, wqA, sc2, sh2);
    gemm_dcn<32, 1, false><<<576, 256, 0, stream>>>(input_x, wqA, nullptr, nullptr, b_off, nullptr, offb);
    build_table<<<1296, 256, 0, stream>>>(offb, tdi, tdw);
    gemm_dcn<256, 4, true><<<576, 256, 0, stream>>>(input_x, wq, tdi, tdw, sc2, sh2, out);
}

// Round 6
// 605.710 us; speedup vs baseline: 1.0729x; 1.0729x over previous
//
#include <hip/hip_runtime.h>
#include <cmath>

#define HH 96
#define WW 96
#define HWsz 9216
#define CCH 256
#define OO 256
#define MTOT 36864
#define NTAP 9

using short8 = __attribute__((ext_vector_type(8))) short;
using f32x4  = __attribute__((ext_vector_type(4))) float;

__device__ __forceinline__ unsigned short f2bf(float f) {
    unsigned u = __float_as_uint(f);
    u += 0x7fff + ((u >> 16) & 1);
    return (unsigned short)(u >> 16);
}

// ---------------- prep ----------------
// wq  [cc][t][kh][o=256][j=8] bf16 : element = w[o][c=cc*32+kh*8+j][t]  (cc-major for t-inner loop)
// wqA [cc][t][kh][o=32][j=8]  bf16 : o>=27 zero, from w_off
// sc2/sh2 [256] : BN scale / shift(+bias)
__global__ __launch_bounds__(256) void prep_kernel(
    const float* __restrict__ w, const float* __restrict__ w_off,
    const float* __restrict__ gamma, const float* __restrict__ beta,
    const float* __restrict__ rmean, const float* __restrict__ rvar,
    const float* __restrict__ bconv,
    unsigned short* __restrict__ wq, unsigned short* __restrict__ wqA,
    float* __restrict__ sc2, float* __restrict__ sh2)
{
    int gid = blockIdx.x * 256 + threadIdx.x;
    if (gid < 589824) {
        int j = gid & 7, o = (gid >> 3) & 255, kh = (gid >> 11) & 3;
        int rem = gid >> 13;            // 0..71
        int t = rem % 9, cc = rem / 9;
        int c = cc * 32 + kh * 8 + j;
        wq[gid] = f2bf(w[(o * 256 + c) * 9 + t]);
        return;
    }
    gid -= 589824;
    if (gid < 73728) {
        int j = gid & 7, o = (gid >> 3) & 31, kh = (gid >> 8) & 3;
        int rem = gid >> 10;
        int t = rem % 9, cc = rem / 9;
        int c = cc * 32 + kh * 8 + j;
        wqA[gid] = (o < 27) ? f2bf(w_off[(o * 256 + c) * 9 + t]) : (unsigned short)0;
        return;
    }
    gid -= 73728;
    if (gid < 256) {
        float s = gamma[gid] * rsqrtf(rvar[gid] + 1e-5f);
        sc2[gid] = s;
        sh2[gid] = beta[gid] - rmean[gid] * s + bconv[gid] * s;
    }
}

// ---------------- build deform table (pair form, SoA [tap][pixel]) ----------------
// val = w.x*x[i.x] + w.y*x[i.x+1] + w.z*x[i.y] + w.w*x[i.y+1]
__global__ __launch_bounds__(256) void build_table(
    const float* __restrict__ off, int2* __restrict__ tbi, float4* __restrict__ tbw)
{
    int e = blockIdx.x * 256 + threadIdx.x;
    if (e >= MTOT * NTAP) return;
    int p = e / 9, t = e - p * 9;
    int b = p / HWsz, hw = p - b * HWsz;
    int h = hw / WW, x = hw % WW;
    const float* ob = off + ((size_t)b * 32) * HWsz + hw;
    float dy = ob[(2 * t) * HWsz];
    float dx = ob[(2 * t + 1) * HWsz];
    float ml = ob[(18 + t) * HWsz];
    float m = 1.f / (1.f + __expf(-ml));
    float py = (float)(h + t / 3 - 1) + dy;
    float px = (float)(x + t % 3 - 1) + dx;
    float y0f = floorf(py), x0f = floorf(px);
    float ly = py - y0f, lx = px - x0f;
    int y0 = (int)y0f, x0 = (int)x0f;
    int y1 = y0 + 1;
    int xb = min(max(x0, 0), WW - 2);
    float cw0 = (xb == x0) ? (1.f - lx) : ((xb == x0 + 1) ? lx : 0.f);
    float cw1 = (xb + 1 == x0) ? (1.f - lx) : ((xb + 1 == x0 + 1) ? lx : 0.f);
    float rt = (y0 >= 0 && y0 <= HH - 1) ? (1.f - ly) : 0.f;
    float rb = (y1 >= 0 && y1 <= HH - 1) ? ly : 0.f;
    int yt = min(max(y0, 0), HH - 1), yb = min(max(y1, 0), HH - 1);
    int2 iv; iv.x = yt * WW + xb; iv.y = yb * WW + xb;
    float4 wv;
    wv.x = rt * cw0 * m; wv.y = rt * cw1 * m;
    wv.z = rb * cw0 * m; wv.w = rb * cw1 * m;
    tbi[(size_t)t * MTOT + p] = iv;
    tbw[(size_t)t * MTOT + p] = wv;
}

// ---------------- implicit GEMM: barrier-free, cc-outer / t-inner ----------------
// Wave = 16 pixels x NOCH och. Lane l: pixel wp0+(l&15), channels cc*32+(l>>4)*8..+7.
// All 9 taps run back-to-back per cc -> gather lines reused in L1/L2.
// 9 bilinear tables preloaded to registers (static t indexing via full unroll).
template<int NOCH, int NCOR, bool PASS2>
__global__ __launch_bounds__(256, 2) void gemm_dcn(
    const float* __restrict__ x,
    const unsigned short* __restrict__ wq,
    const int2* __restrict__ tbi, const float4* __restrict__ tbw,
    const float* __restrict__ ep0, const float* __restrict__ ep1,
    float* __restrict__ outp)
{
    constexpr int NMF = NOCH / 16;
    const int tid  = threadIdx.x;
    const int wid  = tid >> 6;
    const int lane = tid & 63;
    const int l15  = lane & 15;
    const int kh   = lane >> 4;

    const int bid  = blockIdx.x;
    const int mblk = (bid & 7) * ((int)gridDim.x >> 3) + (bid >> 3);
    const int p0   = mblk * 64;
    const int wp0  = p0 + wid * 16;
    const int pg   = wp0 + l15;
    const int img  = p0 / HWsz;
    const int hw0  = pg - img * HWsz;
    const int ph   = hw0 / WW;
    const int pxx  = hw0 - ph * WW;
    const float* __restrict__ xim = x + (size_t)img * CCH * HWsz;

    f32x4 acc[NMF];
    #pragma unroll
    for (int n = 0; n < NMF; ++n) acc[n] = f32x4{0.f, 0.f, 0.f, 0.f};

    // preload per-tap tables into registers (statically indexed below)
    int   tit[NTAP], tib[NTAP];
    float tw0[NTAP], tw1[NTAP], tw2[NTAP], tw3[NTAP];
    if constexpr (NCOR == 4) {
        #pragma unroll
        for (int t = 0; t < NTAP; ++t) {
            int2 iv = tbi[(size_t)t * MTOT + pg];
            float4 wv = tbw[(size_t)t * MTOT + pg];
            tit[t] = iv.x; tib[t] = iv.y;
            tw0[t] = wv.x; tw1[t] = wv.y; tw2[t] = wv.z; tw3[t] = wv.w;
        }
    } else {
        #pragma unroll
        for (int t = 0; t < NTAP; ++t) {
            int yy = ph + t / 3 - 1, xx = pxx + t % 3 - 1;
            bool v = (yy >= 0) && (yy < HH) && (xx >= 0) && (xx < WW);
            tit[t] = v ? yy * WW + xx : 0;
            tib[t] = 0;
            tw0[t] = v ? 1.f : 0.f;
            tw1[t] = tw2[t] = tw3[t] = 0.f;
        }
    }

    #pragma unroll 1
    for (int cc = 0; cc < 8; ++cc) {
        const unsigned cb = (unsigned)(cc * 32 + kh * 8) * HWsz;
        const unsigned short* __restrict__ wcc = wq + (size_t)cc * NTAP * 4 * NOCH * 8;
        #pragma unroll
        for (int t = 0; t < NTAP; ++t) {
            float va[8];
            if constexpr (NCOR == 4) {
                #pragma unroll
                for (int j = 0; j < 8; ++j) {
                    const float* pt = xim + cb + (unsigned)j * HWsz;
                    float t0 = pt[tit[t]], t1 = pt[tit[t] + 1];
                    float b0 = pt[tib[t]], b1 = pt[tib[t] + 1];
                    va[j] = tw0[t] * t0 + tw1[t] * t1 + tw2[t] * b0 + tw3[t] * b1;
                }
            } else {
                #pragma unroll
                for (int j = 0; j < 8; ++j)
                    va[j] = tw0[t] * xim[cb + (unsigned)j * HWsz + tit[t]];
            }
            short8 af;
            #pragma unroll
            for (int j = 0; j < 8; ++j) af[j] = (short)f2bf(va[j]);
            const unsigned short* wb = wcc + (size_t)(t * 4 + kh) * NOCH * 8;
            #pragma unroll
            for (int n = 0; n < NMF; ++n) {
                short8 bfr = *(const short8*)(wb + (n * 16 + l15) * 8);
                acc[n] = __builtin_amdgcn_mfma_f32_16x16x32_bf16(af, bfr, acc[n], 0, 0, 0);
            }
        }
    }

    // ---- epilogue: D rows kh*4+j are contiguous pixels -> float4 stores ----
    const int opix = wp0 - img * HWsz + kh * 4;
    #pragma unroll
    for (int n = 0; n < NMF; ++n) {
        int och = n * 16 + l15;
        float4 vv;
        if constexpr (PASS2) {
            float s0 = ep0[och], s1 = ep1[och];
            vv.x = fmaxf(fmaf(acc[n][0], s0, s1), 0.f);
            vv.y = fmaxf(fmaf(acc[n][1], s0, s1), 0.f);
            vv.z = fmaxf(fmaf(acc[n][2], s0, s1), 0.f);
            vv.w = fmaxf(fmaf(acc[n][3], s0, s1), 0.f);
            *(float4*)&outp[((size_t)img * OO + och) * HWsz + opix] = vv;
        } else {
            if (och < 27) {
                float s1 = ep0[och];
                vv.x = acc[n][0] + s1;
                vv.y = acc[n][1] + s1;
                vv.z = acc[n][2] + s1;
                vv.w = acc[n][3] + s1;
                *(float4*)&outp[((size_t)img * 32 + och) * HWsz + opix] = vv;
            }
        }
    }
}

extern "C" void kernel_launch(void* const* d_in, const int* in_sizes, int n_in,
                              void* d_out, int out_size, void* d_ws, size_t ws_size,
                              hipStream_t stream) {
    const float* input_x = (const float*)d_in[0];
    const float* w_off   = (const float*)d_in[1];
    const float* b_off   = (const float*)d_in[2];
    const float* w       = (const float*)d_in[3];
    const float* b       = (const float*)d_in[4];
    const float* gamma   = (const float*)d_in[5];
    const float* beta    = (const float*)d_in[6];
    const float* rmean   = (const float*)d_in[7];
    const float* rvar    = (const float*)d_in[8];
    float* out = (float*)d_out;

    char* p = (char*)d_ws;
    auto alloc = [&](size_t bytes) {
        char* r = p;
        p += (bytes + 255) & ~(size_t)255;
        return r;
    };
    unsigned short* wq  = (unsigned short*)alloc(589824 * 2);
    unsigned short* wqA = (unsigned short*)alloc(73728 * 2);
    int2*   tdi = (int2*)alloc((size_t)331776 * 8);
    float4* tdw = (float4*)alloc((size_t)331776 * 16);
    float* offb = (float*)alloc((size_t)4 * 32 * 9216 * 4);
    float* sc2 = (float*)alloc(256 * 4);
    float* sh2 = (float*)alloc(256 * 4);

    prep_kernel<<<2593, 256, 0, stream>>>(w, w_off, gamma, beta, rmean, rvar, b,
                                          wq, wqA, sc2, sh2);
    gemm_dcn<32, 1, false><<<576, 256, 0, stream>>>(input_x, wqA, nullptr, nullptr, b_off, nullptr, offb);
    build_table<<<1296, 256, 0, stream>>>(offb, tdi, tdw);
    gemm_dcn<256, 4, true><<<576, 256, 0, stream>>>(input_x, wq, tdi, tdw, sc2, sh2, out);
}

// Round 7
// 458.120 us; speedup vs baseline: 1.4185x; 1.3222x over previous
//
#include <hip/hip_runtime.h>
#include <cmath>

#define HH 96
#define WW 96
#define HWsz 9216
#define CCH 256
#define OO 256
#define MTOT 36864
#define NTAP 9

using short8 = __attribute__((ext_vector_type(8))) short;
using f32x4  = __attribute__((ext_vector_type(4))) float;

__device__ __forceinline__ unsigned short f2bf(float f) {
    unsigned u = __float_as_uint(f);
    u += 0x7fff + ((u >> 16) & 1);
    return (unsigned short)(u >> 16);
}

// ---------------- prep ----------------
// wq  [cc][t][kh][o=256][j=8] bf16 : element = w[o][c=cc*32+kh*8+j][t]
// wqA [cc][t][kh][o=32][j=8]  bf16 : o>=27 zero, from w_off
// sc2/sh2 [256] : BN scale / shift(+bias)
__global__ __launch_bounds__(256) void prep_kernel(
    const float* __restrict__ w, const float* __restrict__ w_off,
    const float* __restrict__ gamma, const float* __restrict__ beta,
    const float* __restrict__ rmean, const float* __restrict__ rvar,
    const float* __restrict__ bconv,
    unsigned short* __restrict__ wq, unsigned short* __restrict__ wqA,
    float* __restrict__ sc2, float* __restrict__ sh2)
{
    int gid = blockIdx.x * 256 + threadIdx.x;
    if (gid < 589824) {
        int j = gid & 7, o = (gid >> 3) & 255, kh = (gid >> 11) & 3;
        int rem = gid >> 13;            // 0..71
        int t = rem % 9, cc = rem / 9;
        int c = cc * 32 + kh * 8 + j;
        wq[gid] = f2bf(w[(o * 256 + c) * 9 + t]);
        return;
    }
    gid -= 589824;
    if (gid < 73728) {
        int j = gid & 7, o = (gid >> 3) & 31, kh = (gid >> 8) & 3;
        int rem = gid >> 10;
        int t = rem % 9, cc = rem / 9;
        int c = cc * 32 + kh * 8 + j;
        wqA[gid] = (o < 27) ? f2bf(w_off[(o * 256 + c) * 9 + t]) : (unsigned short)0;
        return;
    }
    gid -= 73728;
    if (gid < 256) {
        float s = gamma[gid] * rsqrtf(rvar[gid] + 1e-5f);
        sc2[gid] = s;
        sh2[gid] = beta[gid] - rmean[gid] * s + bconv[gid] * s;
    }
}

// ---------------- build deform table (pair form, SoA [tap][pixel]) ----------------
// val = w.x*x[i.x] + w.y*x[i.x+1] + w.z*x[i.y] + w.w*x[i.y+1]
__global__ __launch_bounds__(256) void build_table(
    const float* __restrict__ off, int2* __restrict__ tbi, float4* __restrict__ tbw)
{
    int e = blockIdx.x * 256 + threadIdx.x;
    if (e >= MTOT * NTAP) return;
    int p = e / 9, t = e - p * 9;
    int b = p / HWsz, hw = p - b * HWsz;
    int h = hw / WW, x = hw % WW;
    const float* ob = off + ((size_t)b * 32) * HWsz + hw;
    float dy = ob[(2 * t) * HWsz];
    float dx = ob[(2 * t + 1) * HWsz];
    float ml = ob[(18 + t) * HWsz];
    float m = 1.f / (1.f + __expf(-ml));
    float py = (float)(h + t / 3 - 1) + dy;
    float px = (float)(x + t % 3 - 1) + dx;
    float y0f = floorf(py), x0f = floorf(px);
    float ly = py - y0f, lx = px - x0f;
    int y0 = (int)y0f, x0 = (int)x0f;
    int y1 = y0 + 1;
    int xb = min(max(x0, 0), WW - 2);
    float cw0 = (xb == x0) ? (1.f - lx) : ((xb == x0 + 1) ? lx : 0.f);
    float cw1 = (xb + 1 == x0) ? (1.f - lx) : ((xb + 1 == x0 + 1) ? lx : 0.f);
    float rt = (y0 >= 0 && y0 <= HH - 1) ? (1.f - ly) : 0.f;
    float rb = (y1 >= 0 && y1 <= HH - 1) ? ly : 0.f;
    int yt = min(max(y0, 0), HH - 1), yb = min(max(y1, 0), HH - 1);
    int2 iv; iv.x = yt * WW + xb; iv.y = yb * WW + xb;
    float4 wv;
    wv.x = rt * cw0 * m; wv.y = rt * cw1 * m;
    wv.z = rb * cw0 * m; wv.w = rb * cw1 * m;
    tbi[(size_t)t * MTOT + p] = iv;
    tbw[(size_t)t * MTOT + p] = wv;
}

// ---------------- implicit GEMM: barrier-free, cc-outer / t-inner, pipelined ----------------
// Wave = 16 pixels x NOCH och. Lane l: pixel wp0+(l&15), channels cc*32+(l>>4)*8..+7.
// Gathers for phase p+1 are issued BEFORE phase p's combine (register pipeline, depth 1):
// load latency hides under combine+cvt+MFMA of the current phase.
template<int NOCH, int NCOR, bool PASS2>
__global__ __launch_bounds__(256) void gemm_dcn(
    const float* __restrict__ x,
    const unsigned short* __restrict__ wq,
    const int2* __restrict__ tbi, const float4* __restrict__ tbw,
    const float* __restrict__ ep0, const float* __restrict__ ep1,
    float* __restrict__ outp)
{
    constexpr int NMF = NOCH / 16;
    constexpr int NPD = (NCOR == 4) ? 32 : 8;   // pipeline bank size
    const int tid  = threadIdx.x;
    const int wid  = tid >> 6;
    const int lane = tid & 63;
    const int l15  = lane & 15;
    const int kh   = lane >> 4;

    const int bid  = blockIdx.x;
    const int mblk = (bid & 7) * ((int)gridDim.x >> 3) + (bid >> 3);
    const int p0   = mblk * 64;
    const int wp0  = p0 + wid * 16;
    const int pg   = wp0 + l15;
    const int img  = p0 / HWsz;
    const int hw0  = pg - img * HWsz;
    const int ph   = hw0 / WW;
    const int pxx  = hw0 - ph * WW;
    const float* __restrict__ xim = x + (size_t)img * CCH * HWsz;

    f32x4 acc[NMF];
    #pragma unroll
    for (int n = 0; n < NMF; ++n) acc[n] = f32x4{0.f, 0.f, 0.f, 0.f};

    // preload per-tap tables into registers (statically indexed after unroll)
    int   tit[NTAP], tib[NTAP];
    float tw0[NTAP], tw1[NTAP], tw2[NTAP], tw3[NTAP];
    if constexpr (NCOR == 4) {
        #pragma unroll
        for (int t = 0; t < NTAP; ++t) {
            int2 iv = tbi[(size_t)t * MTOT + pg];
            float4 wv = tbw[(size_t)t * MTOT + pg];
            tit[t] = iv.x; tib[t] = iv.y;
            tw0[t] = wv.x; tw1[t] = wv.y; tw2[t] = wv.z; tw3[t] = wv.w;
        }
    } else {
        #pragma unroll
        for (int t = 0; t < NTAP; ++t) {
            int yy = ph + t / 3 - 1, xx = pxx + t % 3 - 1;
            bool v = (yy >= 0) && (yy < HH) && (xx >= 0) && (xx < WW);
            tit[t] = v ? yy * WW + xx : 0;
            tib[t] = 0;
            tw0[t] = v ? 1.f : 0.f;
            tw1[t] = tw2[t] = tw3[t] = 0.f;
        }
    }

    // issue gathers for (ccx, tx) into dst; tx is unroll-constant at every call
    auto ISSUE = [&](int ccx, int tx, float* dst) {
        const unsigned cb = (unsigned)(ccx * 32 + kh * 8) * HWsz;
        #pragma unroll
        for (int j = 0; j < 8; ++j) {
            const float* __restrict__ pt = xim + cb + (unsigned)j * HWsz;
            if constexpr (NCOR == 4) {
                dst[j * 4 + 0] = pt[tit[tx]];
                dst[j * 4 + 1] = pt[tit[tx] + 1];
                dst[j * 4 + 2] = pt[tib[tx]];
                dst[j * 4 + 3] = pt[tib[tx] + 1];
            } else {
                dst[j] = pt[tit[tx]];
            }
        }
    };

    float pend[NPD];
    ISSUE(0, 0, pend);

    #pragma unroll 1
    for (int cc = 0; cc < 8; ++cc) {
        const unsigned short* __restrict__ wcc = wq + (size_t)cc * NTAP * 4 * NOCH * 8;
        #pragma unroll
        for (int t = 0; t < NTAP; ++t) {
            // 1) issue next phase's gathers first (independent -> fly under the combine's wait)
            float nxtv[NPD];
            if (t < 8)            ISSUE(cc, t + 1, nxtv);
            else if (cc < 7)      ISSUE(cc + 1, 0, nxtv);
            // 2) combine current phase (waits only on pend's older loads)
            float va[8];
            #pragma unroll
            for (int j = 0; j < 8; ++j) {
                if constexpr (NCOR == 4)
                    va[j] = tw0[t] * pend[j * 4 + 0] + tw1[t] * pend[j * 4 + 1]
                          + tw2[t] * pend[j * 4 + 2] + tw3[t] * pend[j * 4 + 3];
                else
                    va[j] = tw0[t] * pend[j];
            }
            short8 af;
            #pragma unroll
            for (int j = 0; j < 8; ++j) af[j] = (short)f2bf(va[j]);
            // 3) B fragments JIT (L1-hot) + MFMA
            const unsigned short* wb = wcc + (size_t)(t * 4 + kh) * NOCH * 8;
            #pragma unroll
            for (int n = 0; n < NMF; ++n) {
                short8 bfr = *(const short8*)(wb + (n * 16 + l15) * 8);
                acc[n] = __builtin_amdgcn_mfma_f32_16x16x32_bf16(af, bfr, acc[n], 0, 0, 0);
            }
            // 4) rotate pipeline bank (SSA-renamed within the unrolled region)
            if (!(cc == 7 && t == 8)) {
                #pragma unroll
                for (int k = 0; k < NPD; ++k) pend[k] = nxtv[k];
            }
        }
    }

    // ---- epilogue: D rows kh*4+j are contiguous pixels -> float4 stores ----
    const int opix = wp0 - img * HWsz + kh * 4;
    #pragma unroll
    for (int n = 0; n < NMF; ++n) {
        int och = n * 16 + l15;
        float4 vv;
        if constexpr (PASS2) {
            float s0 = ep0[och], s1 = ep1[och];
            vv.x = fmaxf(fmaf(acc[n][0], s0, s1), 0.f);
            vv.y = fmaxf(fmaf(acc[n][1], s0, s1), 0.f);
            vv.z = fmaxf(fmaf(acc[n][2], s0, s1), 0.f);
            vv.w = fmaxf(fmaf(acc[n][3], s0, s1), 0.f);
            *(float4*)&outp[((size_t)img * OO + och) * HWsz + opix] = vv;
        } else {
            if (och < 27) {
                float s1 = ep0[och];
                vv.x = acc[n][0] + s1;
                vv.y = acc[n][1] + s1;
                vv.z = acc[n][2] + s1;
                vv.w = acc[n][3] + s1;
                *(float4*)&outp[((size_t)img * 32 + och) * HWsz + opix] = vv;
            }
        }
    }
}

extern "C" void kernel_launch(void* const* d_in, const int* in_sizes, int n_in,
                              void* d_out, int out_size, void* d_ws, size_t ws_size,
                              hipStream_t stream) {
    const float* input_x = (const float*)d_in[0];
    const float* w_off   = (const float*)d_in[1];
    const float* b_off   = (const float*)d_in[2];
    const float* w       = (const float*)d_in[3];
    const float* b       = (const float*)d_in[4];
    const float* gamma   = (const float*)d_in[5];
    const float* beta    = (const float*)d_in[6];
    const float* rmean   = (const float*)d_in[7];
    const float* rvar    = (const float*)d_in[8];
    float* out = (float*)d_out;

    char* p = (char*)d_ws;
    auto alloc = [&](size_t bytes) {
        char* r = p;
        p += (bytes + 255) & ~(size_t)255;
        return r;
    };
    unsigned short* wq  = (unsigned short*)alloc(589824 * 2);
    unsigned short* wqA = (unsigned short*)alloc(73728 * 2);
    int2*   tdi = (int2*)alloc((size_t)331776 * 8);
    float4* tdw = (float4*)alloc((size_t)331776 * 16);
    float* offb = (float*)alloc((size_t)4 * 32 * 9216 * 4);
    float* sc2 = (float*)alloc(256 * 4);
    float* sh2 = (float*)alloc(256 * 4);

    prep_kernel<<<2593, 256, 0, stream>>>(w, w_off, gamma, beta, rmean, rvar, b,
                                          wq, wqA, sc2, sh2);
    gemm_dcn<32, 1, false><<<576, 256, 0, stream>>>(input_x, wqA, nullptr, nullptr, b_off, nullptr, offb);
    build_table<<<1296, 256, 0, stream>>>(offb, tdi, tdw);
    gemm_dcn<256, 4, true><<<576, 256, 0, stream>>>(input_x, wq, tdi, tdw, sc2, sh2, out);
}

// Round 9
// 440.898 us; speedup vs baseline: 1.4739x; 1.0391x over previous
//
#include <hip/hip_runtime.h>
#include <cmath>

#define HH 96
#define WW 96
#define HWsz 9216
#define CCH 256
#define OO 256
#define MTOT 36864
#define NTAP 9

using short8 = __attribute__((ext_vector_type(8))) short;
using f32x4  = __attribute__((ext_vector_type(4))) float;

__device__ __forceinline__ unsigned short f2bf(float f) {
    unsigned u = __float_as_uint(f);
    u += 0x7fff + ((u >> 16) & 1);
    return (unsigned short)(u >> 16);
}

// ---------------- prep ----------------
// wq  [cc][t][kh][o=256][j=8] bf16 : element = w[o][c=cc*32+kh*8+j][t]
// wqA [cc][t][kh][o=32][j=8]  bf16 : o>=27 zero, from w_off
// sc2/sh2 [256] : BN scale / shift(+bias)
__global__ __launch_bounds__(256) void prep_kernel(
    const float* __restrict__ w, const float* __restrict__ w_off,
    const float* __restrict__ gamma, const float* __restrict__ beta,
    const float* __restrict__ rmean, const float* __restrict__ rvar,
    const float* __restrict__ bconv,
    unsigned short* __restrict__ wq, unsigned short* __restrict__ wqA,
    float* __restrict__ sc2, float* __restrict__ sh2)
{
    int gid = blockIdx.x * 256 + threadIdx.x;
    if (gid < 589824) {
        int j = gid & 7, o = (gid >> 3) & 255, kh = (gid >> 11) & 3;
        int rem = gid >> 13;            // 0..71
        int t = rem % 9, cc = rem / 9;
        int c = cc * 32 + kh * 8 + j;
        wq[gid] = f2bf(w[(o * 256 + c) * 9 + t]);
        return;
    }
    gid -= 589824;
    if (gid < 73728) {
        int j = gid & 7, o = (gid >> 3) & 31, kh = (gid >> 8) & 3;
        int rem = gid >> 10;
        int t = rem % 9, cc = rem / 9;
        int c = cc * 32 + kh * 8 + j;
        wqA[gid] = (o < 27) ? f2bf(w_off[(o * 256 + c) * 9 + t]) : (unsigned short)0;
        return;
    }
    gid -= 73728;
    if (gid < 256) {
        float s = gamma[gid] * rsqrtf(rvar[gid] + 1e-5f);
        sc2[gid] = s;
        sh2[gid] = beta[gid] - rmean[gid] * s + bconv[gid] * s;
    }
}

// ---------------- build deform table (pair form, SoA [tap][pixel]) ----------------
// val = w.x*x[i.x] + w.y*x[i.x+1] + w.z*x[i.y] + w.w*x[i.y+1]
__global__ __launch_bounds__(256) void build_table(
    const float* __restrict__ off, int2* __restrict__ tbi, float4* __restrict__ tbw)
{
    int e = blockIdx.x * 256 + threadIdx.x;
    if (e >= MTOT * NTAP) return;
    int p = e / 9, t = e - p * 9;
    int b = p / HWsz, hw = p - b * HWsz;
    int h = hw / WW, x = hw % WW;
    const float* ob = off + ((size_t)b * 32) * HWsz + hw;
    float dy = ob[(2 * t) * HWsz];
    float dx = ob[(2 * t + 1) * HWsz];
    float ml = ob[(18 + t) * HWsz];
    float m = 1.f / (1.f + __expf(-ml));
    float py = (float)(h + t / 3 - 1) + dy;
    float px = (float)(x + t % 3 - 1) + dx;
    float y0f = floorf(py), x0f = floorf(px);
    float ly = py - y0f, lx = px - x0f;
    int y0 = (int)y0f, x0 = (int)x0f;
    int y1 = y0 + 1;
    int xb = min(max(x0, 0), WW - 2);
    float cw0 = (xb == x0) ? (1.f - lx) : ((xb == x0 + 1) ? lx : 0.f);
    float cw1 = (xb + 1 == x0) ? (1.f - lx) : ((xb + 1 == x0 + 1) ? lx : 0.f);
    float rt = (y0 >= 0 && y0 <= HH - 1) ? (1.f - ly) : 0.f;
    float rb = (y1 >= 0 && y1 <= HH - 1) ? ly : 0.f;
    int yt = min(max(y0, 0), HH - 1), yb = min(max(y1, 0), HH - 1);
    int2 iv; iv.x = yt * WW + xb; iv.y = yb * WW + xb;
    float4 wv;
    wv.x = rt * cw0 * m; wv.y = rt * cw1 * m;
    wv.z = rb * cw0 * m; wv.w = rb * cw1 * m;
    tbi[(size_t)t * MTOT + p] = iv;
    tbw[(size_t)t * MTOT + p] = wv;
}

// ---------------- implicit GEMM: barrier-free, cc-outer / t-inner, pipelined ----------------
// Wave = 16 pixels x NOCH och. Lane l: pixel wp0+(l&15), channels cc*32+(l>>4)*8..+7.
// Per-phase VMEM issue order is pinned (sched_barrier):
//   [B frags (oldest)] -> [next-phase gathers] -> combine(pend) -> MFMA.
// MFMA's wait on B = vmcnt(32): the 32 prefetch gathers STAY IN FLIGHT across
// the MFMA (previously B was youngest -> vmcnt(0) drained the pipeline).
template<int NOCH, int NCOR, bool PASS2>
__global__ __launch_bounds__(256) void gemm_dcn(
    const float* __restrict__ x,
    const unsigned short* __restrict__ wq,
    const int2* __restrict__ tbi, const float4* __restrict__ tbw,
    const float* __restrict__ ep0, const float* __restrict__ ep1,
    float* __restrict__ outp)
{
    constexpr int NMF = NOCH / 16;
    constexpr int NPD = (NCOR == 4) ? 32 : 8;   // pipeline bank size
    const int tid  = threadIdx.x;
    const int wid  = tid >> 6;
    const int lane = tid & 63;
    const int l15  = lane & 15;
    const int kh   = lane >> 4;

    const int bid  = blockIdx.x;
    const int mblk = (bid & 7) * ((int)gridDim.x >> 3) + (bid >> 3);
    const int p0   = mblk * 64;
    const int wp0  = p0 + wid * 16;
    const int pg   = wp0 + l15;
    const int img  = p0 / HWsz;
    const int hw0  = pg - img * HWsz;
    const int ph   = hw0 / WW;
    const int pxx  = hw0 - ph * WW;
    const float* __restrict__ xim = x + (size_t)img * CCH * HWsz;

    f32x4 acc[NMF];
    #pragma unroll
    for (int n = 0; n < NMF; ++n) acc[n] = f32x4{0.f, 0.f, 0.f, 0.f};

    // preload per-tap tables into registers (statically indexed after unroll)
    int   tit[NTAP], tib[NTAP];
    float tw0[NTAP], tw1[NTAP], tw2[NTAP], tw3[NTAP];
    if constexpr (NCOR == 4) {
        #pragma unroll
        for (int t = 0; t < NTAP; ++t) {
            int2 iv = tbi[(size_t)t * MTOT + pg];
            float4 wv = tbw[(size_t)t * MTOT + pg];
            tit[t] = iv.x; tib[t] = iv.y;
            tw0[t] = wv.x; tw1[t] = wv.y; tw2[t] = wv.z; tw3[t] = wv.w;
        }
    } else {
        #pragma unroll
        for (int t = 0; t < NTAP; ++t) {
            int yy = ph + t / 3 - 1, xx = pxx + t % 3 - 1;
            bool v = (yy >= 0) && (yy < HH) && (xx >= 0) && (xx < WW);
            tit[t] = v ? yy * WW + xx : 0;
            tib[t] = 0;
            tw0[t] = v ? 1.f : 0.f;
            tw1[t] = tw2[t] = tw3[t] = 0.f;
        }
    }

    // issue gathers for (ccx, tx) into dst; tx is unroll-constant at every call
    auto ISSUE = [&](int ccx, int tx, float* dst) {
        const unsigned cb = (unsigned)(ccx * 32 + kh * 8) * HWsz;
        #pragma unroll
        for (int j = 0; j < 8; ++j) {
            const float* __restrict__ pt = xim + cb + (unsigned)j * HWsz;
            if constexpr (NCOR == 4) {
                dst[j * 4 + 0] = pt[tit[tx]];
                dst[j * 4 + 1] = pt[tit[tx] + 1];
                dst[j * 4 + 2] = pt[tib[tx]];
                dst[j * 4 + 3] = pt[tib[tx] + 1];
            } else {
                dst[j] = pt[tit[tx]];
            }
        }
    };

    float pend[NPD];
    ISSUE(0, 0, pend);

    #pragma unroll 1
    for (int cc = 0; cc < 8; ++cc) {
        const unsigned short* __restrict__ wcc = wq + (size_t)cc * NTAP * 4 * NOCH * 8;
        #pragma unroll
        for (int t = 0; t < NTAP; ++t) {
            // 1) B fragments for CURRENT phase first -> oldest loads in this
            //    phase's batch; MFMA's wait on them leaves younger gathers in flight
            short8 bfr[NMF];
            const unsigned short* wb = wcc + (size_t)(t * 4 + kh) * NOCH * 8;
            #pragma unroll
            for (int n = 0; n < NMF; ++n)
                bfr[n] = *(const short8*)(wb + (n * 16 + l15) * 8);
            __builtin_amdgcn_sched_barrier(0);
            // 2) issue next phase's gathers (younger than B)
            float nxtv[NPD];
            if (t < 8)            ISSUE(cc, t + 1, nxtv);
            else if (cc < 7)      ISSUE(cc + 1, 0, nxtv);
            __builtin_amdgcn_sched_barrier(0);
            // 3) combine current phase (pend loads are one full phase old)
            float va[8];
            #pragma unroll
            for (int j = 0; j < 8; ++j) {
                if constexpr (NCOR == 4)
                    va[j] = tw0[t] * pend[j * 4 + 0] + tw1[t] * pend[j * 4 + 1]
                          + tw2[t] * pend[j * 4 + 2] + tw3[t] * pend[j * 4 + 3];
                else
                    va[j] = tw0[t] * pend[j];
            }
            short8 af;
            #pragma unroll
            for (int j = 0; j < 8; ++j) af[j] = (short)f2bf(va[j]);
            // 4) MFMA: waits vmcnt(32) for bfr only; nxtv stays outstanding
            #pragma unroll
            for (int n = 0; n < NMF; ++n)
                acc[n] = __builtin_amdgcn_mfma_f32_16x16x32_bf16(af, bfr[n], acc[n], 0, 0, 0);
            // 5) rotate pipeline bank (SSA-renamed within the unrolled region)
            if (!(cc == 7 && t == 8)) {
                #pragma unroll
                for (int k = 0; k < NPD; ++k) pend[k] = nxtv[k];
            }
        }
    }

    // ---- epilogue: D rows kh*4+j are contiguous pixels -> float4 stores ----
    const int opix = wp0 - img * HWsz + kh * 4;
    #pragma unroll
    for (int n = 0; n < NMF; ++n) {
        int och = n * 16 + l15;
        float4 vv;
        if constexpr (PASS2) {
            float s0 = ep0[och], s1 = ep1[och];
            vv.x = fmaxf(fmaf(acc[n][0], s0, s1), 0.f);
            vv.y = fmaxf(fmaf(acc[n][1], s0, s1), 0.f);
            vv.z = fmaxf(fmaf(acc[n][2], s0, s1), 0.f);
            vv.w = fmaxf(fmaf(acc[n][3], s0, s1), 0.f);
            *(float4*)&outp[((size_t)img * OO + och) * HWsz + opix] = vv;
        } else {
            if (och < 27) {
                float s1 = ep0[och];
                vv.x = acc[n][0] + s1;
                vv.y = acc[n][1] + s1;
                vv.z = acc[n][2] + s1;
                vv.w = acc[n][3] + s1;
                *(float4*)&outp[((size_t)img * 32 + och) * HWsz + opix] = vv;
            }
        }
    }
}

extern "C" void kernel_launch(void* const* d_in, const int* in_sizes, int n_in,
                              void* d_out, int out_size, void* d_ws, size_t ws_size,
                              hipStream_t stream) {
    const float* input_x = (const float*)d_in[0];
    const float* w_off   = (const float*)d_in[1];
    const float* b_off   = (const float*)d_in[2];
    const float* w       = (const float*)d_in[3];
    const float* b       = (const float*)d_in[4];
    const float* gamma   = (const float*)d_in[5];
    const float* beta    = (const float*)d_in[6];
    const float* rmean   = (const float*)d_in[7];
    const float* rvar    = (const float*)d_in[8];
    float* out = (float*)d_out;

    char* p = (char*)d_ws;
    auto alloc = [&](size_t bytes) {
        char* r = p;
        p += (bytes + 255) & ~(size_t)255;
        return r;
    };
    unsigned short* wq  = (unsigned short*)alloc(589824 * 2);
    unsigned short* wqA = (unsigned short*)alloc(73728 * 2);
    int2*   tdi = (int2*)alloc((size_t)331776 * 8);
    float4* tdw = (float4*)alloc((size_t)331776 * 16);
    float* offb = (float*)alloc((size_t)4 * 32 * 9216 * 4);
    float* sc2 = (float*)alloc(256 * 4);
    float* sh2 = (float*)alloc(256 * 4);

    prep_kernel<<<2593, 256, 0, stream>>>(w, w_off, gamma, beta, rmean, rvar, b,
                                          wq, wqA, sc2, sh2);
    gemm_dcn<32, 1, false><<<576, 256, 0, stream>>>(input_x, wqA, nullptr, nullptr, b_off, nullptr, offb);
    build_table<<<1296, 256, 0, stream>>>(offb, tdi, tdw);
    gemm_dcn<256, 4, true><<<576, 256, 0, stream>>>(input_x, wq, tdi, tdw, sc2, sh2, out);
}